// Round 6
// baseline (937.060 us; speedup 1.0000x reference)
//
#include <hip/hip_runtime.h>
#include <hip/hip_bf16.h>

// Problem constants
#define B_   256
#define L_   512
#define D_   768
#define H_   1000   // ATTN_H
#define NPAD 1024   // H_ padded to MFMA tile
#define XDIM 2324   // 2*D + D + 20
#define MAXPOS (B_*L_)   // 131072
#define NKC  24     // K chunks of 32 (768/32)

typedef _Float16 half8 __attribute__((ext_vector_type(8)));
typedef float    f32x4 __attribute__((ext_vector_type(4)));

// ---------------------------------------------------------------------------
// Kernel 1: per-batch width scan (1 block).
__global__ __launch_bounds__(256) void scan_kernel(const int* __restrict__ spans,
                                                   int* __restrict__ meta) {
    int b = threadIdx.x;
    int s = spans[2 * b], e = spans[2 * b + 1];
    s = min(max(s, 0), L_ - 1);
    e = min(max(e, s), L_ - 1);
    int w = e - s + 1;
    __shared__ int sw[256];
    sw[b] = w;
    __syncthreads();
    for (int d = 1; d < 256; d <<= 1) {
        int v = 0;
        if (b >= d) v = sw[b - d];
        __syncthreads();
        if (b >= d) sw[b] += v;
        __syncthreads();
    }
    meta[b]       = sw[b] - w;
    meta[256 + b] = s;
    meta[512 + b] = e;
    if (b == 255) meta[768] = sw[255];
}

// Kernel 2: compacted (b,l) position list
__global__ __launch_bounds__(256) void pos_fill(const int* __restrict__ meta,
                                                int* __restrict__ pos_list) {
    int b = blockIdx.x;
    int off = meta[b], start = meta[256 + b], end = meta[512 + b];
    int w = end - start + 1;
    for (int i = threadIdx.x; i < w; i += blockDim.x)
        pos_list[off + i] = (b << 16) | (start + i);
}

// ---------------------------------------------------------------------------
// Kernel 3: pack aw1 into MFMA-fragment order (coalesced B loads).
// Bp[((gi*NKC + kc)*64 + lane)*8 + e] = f16(aw1[k][col]), col=gi*16+(lane&15),
// k = kc*32 + (lane>>4)*8 + e  (zero for col >= H_).
__global__ __launch_bounds__(64) void pack_b(const float* __restrict__ aw1,
                                             _Float16* __restrict__ Bp) {
    int gi = blockIdx.x, kc = blockIdx.y;
    int l = threadIdx.x;
    int col = gi * 16 + (l & 15);
    int kbase = kc * 32 + (l >> 4) * 8;
    half8 h;
#pragma unroll
    for (int e = 0; e < 8; e++) {
        float v = (col < H_) ? aw1[(size_t)(kbase + e) * H_ + col] : 0.f;
        h[e] = (_Float16)v;
    }
    *(half8*)&Bp[(((size_t)gi * NKC + kc) * 64 + l) * 8] = h;
}

// ---------------------------------------------------------------------------
// Kernel 4: barrier-free MFMA GEMM + fused leaky/aw2-dot epilogue.
// Block = 32 rows (A resident in LDS). Wave w owns cols [w*256, w*256+256) in
// 4 groups of 64. B frags: pre-packed coalesced loads, 2-stage reg dbuf.
#define AP 776   // 768 + 8 pad
__global__ __launch_bounds__(256) void attn_gemm_v2(
    const float* __restrict__ embeds, const _Float16* __restrict__ Bp,
    const float* __restrict__ ab1, const float* __restrict__ aw2,
    const int* __restrict__ pos_list, const int* __restrict__ meta,
    float* __restrict__ attns) {
    int npos = meta[768];
    int m0 = blockIdx.x * 32;
    if (m0 >= npos) return;
    int t = threadIdx.x;
    int lane = t & 63, w = t >> 6;
    int q = lane >> 4, l15 = lane & 15;

    __shared__ alignas(16) _Float16 As[32][AP];
    __shared__ unsigned rowoff[32];
    __shared__ float attns_s[4][32];

    if (t < 32) {
        unsigned off = 0;
        int m = m0 + t;
        if (m < npos) {
            int p = pos_list[m];
            off = (unsigned)((p >> 16) * (L_ * D_) + (p & 0xffff) * D_);
        }
        rowoff[t] = off;
    }
    __syncthreads();

    {   // Stage A: thread t -> row t>>3, 96 floats at col (t&7)*96, fp32->f16
        int row = t >> 3;
        int cs = (t & 7) * 96;
        const float* src = embeds + rowoff[row] + cs;
#pragma unroll
        for (int i2 = 0; i2 < 12; i2++) {
            float4 v0 = *(const float4*)(src + i2 * 8);
            float4 v1 = *(const float4*)(src + i2 * 8 + 4);
            half8 h;
            h[0] = (_Float16)v0.x; h[1] = (_Float16)v0.y;
            h[2] = (_Float16)v0.z; h[3] = (_Float16)v0.w;
            h[4] = (_Float16)v1.x; h[5] = (_Float16)v1.y;
            h[6] = (_Float16)v1.z; h[7] = (_Float16)v1.w;
            *(half8*)&As[row][cs + i2 * 8] = h;
        }
    }
    __syncthreads();

    float pacc[2][4];
#pragma unroll
    for (int i = 0; i < 2; i++)
#pragma unroll
        for (int r = 0; r < 4; r++) pacc[i][r] = 0.f;

    for (int g = 0; g < 4; g++) {
        int colbase = w * 256 + g * 64;
        int gi0 = colbase >> 4;                      // first 16-col group (of 4)
        const _Float16* bb = Bp + ((size_t)gi0 * NKC * 64) * 8 + (size_t)lane * 8;
        // frag stride between kc: 64*8 halves; between j-groups: NKC*64*8 halves
        f32x4 acc[2][4];
#pragma unroll
        for (int i = 0; i < 2; i++)
#pragma unroll
            for (int j = 0; j < 4; j++) acc[i][j] = (f32x4){0.f, 0.f, 0.f, 0.f};

        half8 bfA[4], bfB[4];
#pragma unroll
        for (int j = 0; j < 4; j++)
            bfA[j] = *(const half8*)(bb + (size_t)j * (NKC * 64 * 8));

        for (int kc = 0; kc < NKC; kc += 2) {
            // prefetch kc+1 into B-buf
#pragma unroll
            for (int j = 0; j < 4; j++)
                bfB[j] = *(const half8*)(bb + (size_t)j * (NKC * 64 * 8) + (size_t)(kc + 1) * 512);
            {
                half8 af[2];
#pragma unroll
                for (int i = 0; i < 2; i++)
                    af[i] = *(const half8*)&As[l15 + 16 * i][kc * 32 + q * 8];
#pragma unroll
                for (int i = 0; i < 2; i++)
#pragma unroll
                    for (int j = 0; j < 4; j++)
                        acc[i][j] = __builtin_amdgcn_mfma_f32_16x16x32_f16(af[i], bfA[j], acc[i][j], 0, 0, 0);
            }
            // prefetch kc+2 into A-buf
            if (kc + 2 < NKC) {
#pragma unroll
                for (int j = 0; j < 4; j++)
                    bfA[j] = *(const half8*)(bb + (size_t)j * (NKC * 64 * 8) + (size_t)(kc + 2) * 512);
            }
            {
                half8 af[2];
#pragma unroll
                for (int i = 0; i < 2; i++)
                    af[i] = *(const half8*)&As[l15 + 16 * i][(kc + 1) * 32 + q * 8];
#pragma unroll
                for (int i = 0; i < 2; i++)
#pragma unroll
                    for (int j = 0; j < 4; j++)
                        acc[i][j] = __builtin_amdgcn_mfma_f32_16x16x32_f16(af[i], bfB[j], acc[i][j], 0, 0, 0);
            }
        }

        float bj[4], aj[4];
#pragma unroll
        for (int j = 0; j < 4; j++) {
            int col = colbase + j * 16 + l15;
            bool v = col < H_;
            bj[j] = v ? ab1[col] : 0.f;
            aj[j] = v ? aw2[col] : 0.f;
        }
#pragma unroll
        for (int i = 0; i < 2; i++) {
#pragma unroll
            for (int r = 0; r < 4; r++) {
                float p = 0.f;
#pragma unroll
                for (int j = 0; j < 4; j++) {
                    float h = acc[i][j][r] + bj[j];
                    h = h > 0.f ? h : 0.01f * h;
                    p += h * aj[j];
                }
                p += __shfl_xor(p, 1);
                p += __shfl_xor(p, 2);
                p += __shfl_xor(p, 4);
                p += __shfl_xor(p, 8);
                pacc[i][r] += p;
            }
        }
    }
    if (l15 == 0) {
#pragma unroll
        for (int i = 0; i < 2; i++)
#pragma unroll
            for (int r = 0; r < 4; r++)
                attns_s[w][i * 16 + q * 4 + r] = pacc[i][r];
    }
    __syncthreads();
    if (t < 32 && m0 + t < npos)
        attns[m0 + t] = attns_s[0][t] + attns_s[1][t] + attns_s[2][t] + attns_s[3][t];
}

// ---------------------------------------------------------------------------
// Kernel 5: softmax + weighted sum, 3 dim-slices per batch, 8-deep ILP.
__global__ __launch_bounds__(256) void build_x(
    const float* __restrict__ embeds, const float* __restrict__ attns,
    const int* __restrict__ meta, const float* __restrict__ width_emb,
    float* __restrict__ x) {
    int b = blockIdx.x, s = blockIdx.y, t = threadIdx.x;
    int off = meta[b], start = meta[256 + b], end = meta[512 + b];
    int w = end - start + 1;
    __shared__ float sv[512];
    __shared__ float red[256];
    for (int i = t; i < w; i += 256) sv[i] = attns[off + i];
    __syncthreads();
    float m = -3.0e38f;
    for (int i = t; i < w; i += 256) m = fmaxf(m, sv[i]);
    red[t] = m;
    __syncthreads();
    for (int st = 128; st > 0; st >>= 1) {
        if (t < st) red[t] = fmaxf(red[t], red[t + st]);
        __syncthreads();
    }
    float mx = red[0];
    __syncthreads();
    float ssum = 0.f;
    for (int i = t; i < w; i += 256) {
        float e = __expf(sv[i] - mx);
        sv[i] = e;
        ssum += e;
    }
    red[t] = ssum;
    __syncthreads();
    for (int st = 128; st > 0; st >>= 1) {
        if (t < st) red[t] += red[t + st];
        __syncthreads();
    }
    float inv = 1.0f / red[0];
    __syncthreads();

    int dim = s * 256 + t;
    const float* base = embeds + ((size_t)b * L_ + start) * D_ + dim;
    float a0 = 0.f, a1 = 0.f, a2 = 0.f, a3 = 0.f;
    float a4 = 0.f, a5 = 0.f, a6 = 0.f, a7 = 0.f;
    int i = 0;
    for (; i + 8 <= w; i += 8) {
        const float* p = base + (size_t)i * D_;
        a0 += sv[i]     * p[0];
        a1 += sv[i + 1] * p[D_];
        a2 += sv[i + 2] * p[2 * D_];
        a3 += sv[i + 3] * p[3 * D_];
        a4 += sv[i + 4] * p[4 * D_];
        a5 += sv[i + 5] * p[5 * D_];
        a6 += sv[i + 6] * p[6 * D_];
        a7 += sv[i + 7] * p[7 * D_];
    }
    for (; i < w; i++) a0 += sv[i] * base[(size_t)i * D_];
    float acc = ((a0 + a1) + (a2 + a3)) + ((a4 + a5) + (a6 + a7));

    float* xb = x + (size_t)b * XDIM;
    xb[1536 + dim] = acc * inv;
    xb[dim]        = base[0];
    xb[768 + dim]  = embeds[((size_t)b * L_ + end) * D_ + dim];
    if (s == 0 && t < 20) {
        const int bins[15] = {1, 2, 3, 4, 5, 6, 7, 8, 12, 16, 20, 24, 32, 64, 128};
        int idx = 0;
#pragma unroll
        for (int q2 = 0; q2 < 15; q2++) idx += (w > bins[q2]);
        xb[2304 + t] = width_emb[idx * 20 + t];
    }
}

// ---------------------------------------------------------------------------
// Kernel 6: split-K fp32 GEMM. (R5-validated)
__global__ __launch_bounds__(256) void mlp_gemm_sk(
    const float* __restrict__ A, const float* __restrict__ W,
    float* __restrict__ out, int M, int N, int K, int kchunk) {
    __shared__ float As[16][68];
    __shared__ float Ws[16][64];
    int t = threadIdx.x;
    int tx = t & 15, ty = t >> 4;
    int m0 = blockIdx.x * 64, n0 = blockIdx.y * 64;
    int ks = blockIdx.z * kchunk;
    int ke = min(ks + kchunk, K);
    if (ks >= ke) return;
    int ar = t >> 2, akc = (t & 3) * 4;
    int wk = t >> 4, wnc = (t & 15) * 4;
    bool n4 = ((N & 3) == 0);

    float acc[4][4];
#pragma unroll
    for (int i = 0; i < 4; i++)
#pragma unroll
        for (int j = 0; j < 4; j++) acc[i][j] = 0.f;

    auto loadA = [&](int k0) -> float4 {
        float4 r = make_float4(0.f, 0.f, 0.f, 0.f);
        int k = k0 + akc;
        if (k < ke) r = *(const float4*)(A + (size_t)(m0 + ar) * K + k);
        return r;
    };
    auto loadW = [&](int k0) -> float4 {
        float4 r = make_float4(0.f, 0.f, 0.f, 0.f);
        int k = k0 + wk;
        if (k < ke) {
            int n = n0 + wnc;
            const float* p = W + (size_t)k * N + n;
            if (n4) {
                r = *(const float4*)p;
            } else {
                float tmp[4];
#pragma unroll
                for (int q2 = 0; q2 < 4; q2++)
                    tmp[q2] = (n + q2 < N) ? p[q2] : 0.f;
                r = make_float4(tmp[0], tmp[1], tmp[2], tmp[3]);
            }
        }
        return r;
    };

    float4 aR = loadA(ks), wR = loadW(ks);
    for (int k0 = ks; k0 < ke; k0 += 16) {
        As[akc + 0][ar] = aR.x;
        As[akc + 1][ar] = aR.y;
        As[akc + 2][ar] = aR.z;
        As[akc + 3][ar] = aR.w;
        *(float4*)&Ws[wk][wnc] = wR;
        __syncthreads();
        if (k0 + 16 < ke) { aR = loadA(k0 + 16); wR = loadW(k0 + 16); }
#pragma unroll
        for (int kk = 0; kk < 16; kk++) {
            float4 a = *(const float4*)&As[kk][ty * 4];
            float4 b = *(const float4*)&Ws[kk][tx * 4];
            float av[4] = {a.x, a.y, a.z, a.w};
            float bv[4] = {b.x, b.y, b.z, b.w};
#pragma unroll
            for (int i = 0; i < 4; i++)
#pragma unroll
                for (int j = 0; j < 4; j++) acc[i][j] += av[i] * bv[j];
        }
        __syncthreads();
    }
#pragma unroll
    for (int i = 0; i < 4; i++) {
#pragma unroll
        for (int j = 0; j < 4; j++) {
            int nn = n0 + tx * 4 + j;
            if (nn < N)
                atomicAdd(&out[(size_t)(m0 + ty * 4 + i) * N + nn], acc[i][j]);
        }
    }
}

// Kernel 7: elementwise bias (+ optional leaky)
__global__ __launch_bounds__(256) void bias_act(
    const float* __restrict__ src, const float* __restrict__ bias,
    float* __restrict__ dst, int total, int N, int leaky) {
    int i = blockIdx.x * 256 + threadIdx.x;
    int stride = gridDim.x * 256;
    for (; i < total; i += stride) {
        float v = src[i] + bias[i % N];
        if (leaky) v = v > 0.f ? v : 0.01f * v;
        dst[i] = v;
    }
}

// ---------------------------------------------------------------------------
extern "C" void kernel_launch(void* const* d_in, const int* in_sizes, int n_in,
                              void* d_out, int out_size, void* d_ws, size_t ws_size,
                              hipStream_t stream) {
    const float* embeds    = (const float*)d_in[0];
    const int*   spans     = (const int*)d_in[1];   // int64 ref -> int32 device
    const float* aw1       = (const float*)d_in[2];
    const float* ab1       = (const float*)d_in[3];
    const float* aw2       = (const float*)d_in[4];
    // d_in[5] = ab2: softmax shift-invariant -> unused
    const float* width_emb = (const float*)d_in[6];
    const float* sw1 = (const float*)d_in[7],  *sb1 = (const float*)d_in[8];
    const float* sw2 = (const float*)d_in[9],  *sb2 = (const float*)d_in[10];
    const float* sw3 = (const float*)d_in[11], *sb3 = (const float*)d_in[12];
    const float* sw4 = (const float*)d_in[13], *sb4 = (const float*)d_in[14];
    float* out = (float*)d_out;

    char* ws = (char*)d_ws;
    float*     attns    = (float*)ws;                              // 512 KB
    int*       pos_list = (int*)(ws + (size_t)MAXPOS * 4);         // 512 KB
    int*       meta     = (int*)(ws + (size_t)MAXPOS * 8);         // 4 KB
    _Float16*  Bp       = (_Float16*)(ws + (size_t)MAXPOS * 8 + 4096);  // 1.5 MB
    float* x  = (float*)(ws + (size_t)MAXPOS * 8 + 4096 + (size_t)NPAD * D_ * 2);
    float* y1 = x + (size_t)B_ * XDIM;        // 256*1024
    float* y2 = y1 + (size_t)B_ * 1024;       // 256*512
    float* y3 = y2 + (size_t)B_ * 512;        // 256*256
    float* y4 = y3 + (size_t)B_ * 256;        // 256*30
    size_t ybytes = ((size_t)B_ * (1024 + 512 + 256 + 30)) * 4;

    hipMemsetAsync(y1, 0, ybytes, stream);    // split-K accumulators
    scan_kernel<<<1, 256, 0, stream>>>(spans, meta);
    pos_fill<<<B_, 256, 0, stream>>>(meta, pos_list);
    pack_b<<<dim3(NPAD / 16, NKC), 64, 0, stream>>>(aw1, Bp);
    attn_gemm_v2<<<MAXPOS / 32, 256, 0, stream>>>(
        embeds, Bp, ab1, aw2, pos_list, meta, attns);
    build_x<<<dim3(B_, 3), 256, 0, stream>>>(embeds, attns, meta, width_emb, x);

    mlp_gemm_sk<<<dim3(4, 16, 8), 256, 0, stream>>>(x,  sw1, y1, B_, 1024, XDIM, 292);
    bias_act<<<256, 256, 0, stream>>>(y1, sb1, y1, B_ * 1024, 1024, 1);
    mlp_gemm_sk<<<dim3(4, 8, 8), 256, 0, stream>>>(y1, sw2, y2, B_, 512, 1024, 128);
    bias_act<<<128, 256, 0, stream>>>(y2, sb2, y2, B_ * 512, 512, 1);
    mlp_gemm_sk<<<dim3(4, 4, 8), 256, 0, stream>>>(y2, sw3, y3, B_, 256, 512, 64);
    bias_act<<<64, 256, 0, stream>>>(y3, sb3, y3, B_ * 256, 256, 1);
    mlp_gemm_sk<<<dim3(4, 1, 8), 256, 0, stream>>>(y3, sw4, y4, B_, 30, 256, 32);
    bias_act<<<30, 256, 0, stream>>>(y4, sb4, out, B_ * 30, 30, 0);
}